// Round 6
// baseline (89.947 us; speedup 1.0000x reference)
//
#include <hip/hip_runtime.h>
#include <hip/hip_bf16.h>

// AttentionNTKChoiceModel — 2-dispatch grid-resident version.
// B=32, L=512, D=128, H=8, D0=D2=32.
//
// k1 (convert_w): Wc[576,256]bf16 hi|lo split of [W1;W2;u;0pad], u folded
//                 (u_h = sum_d w[h,d]*W3[h*32+d,:]/sqrt(8)); resets barrier.
// k2 (mega), grid 256 x 512thr, LDS 115.5 KB -> exactly 1 block/CU -> all
//    256 blocks co-resident -> software grid barrier (device-scope atomics,
//    timeout-guarded) is safe. Phases:
//    P1 proj: block=(rowblk,colhalf): 128 rows x 288 cols. X f32 staged+
//       bf16-split in LDS once; Wc col-chunks of 96 staged per iter.
//       acc = X.[Wd] + X.[Wd shifted by 128] = exact 4-term hi/lo product.
//       Epilogue -> per-head Q2/K2 [B,H,L,64]bf16 (hi|lo, Q pre-scaled by
//       1/sqrt(32)*log2e), Vw[B,H,L]f32.
//    P2 attn: block=(b,h): whole 512-key head staged in LDS, scores^T=K@Q^T
//       3-term (hh+hl+lh), online softmax in exp2 domain, val+=p*Vw -> vws.
//    P3 final (blocks 0..31): sum heads, q-mask, 512-wide softmax -> out.

typedef __attribute__((ext_vector_type(8))) short bf16x8;
typedef __attribute__((ext_vector_type(4))) float f32x4;
typedef __attribute__((ext_vector_type(8))) unsigned short ushort8;
typedef __attribute__((ext_vector_type(4))) unsigned short ushort4v;

#define NEG (-10000.0f)
#define LOG2E 1.4426950408889634f
#define QSCALE (0.17677669529663687f * LOG2E)

__device__ __forceinline__ unsigned short bf16_rn(float x, float* rep) {
  unsigned u = __float_as_uint(x);
  unsigned r = (u + 0x7FFFu + ((u >> 16) & 1u)) >> 16;
  *rep = __uint_as_float(r << 16);
  return (unsigned short)r;
}

// grid 33 x 256
__global__ __launch_bounds__(256) void convert_w_kernel(
    const float* __restrict__ W1, const float* __restrict__ W2,
    const float* __restrict__ W3, const float* __restrict__ w,
    unsigned short* __restrict__ Wc, int* __restrict__ bar) {
  const int bx = blockIdx.x, t = threadIdx.x;
  if (bx < 32) {
    const int flat = bx * 2048 + t * 8;
    const int row = flat >> 7, c = flat & 127;
    const float* src = (row < 256) ? &W1[(size_t)row * 128 + c]
                                   : &W2[(size_t)(row - 256) * 128 + c];
    float xv[8];
    *(float4*)&xv[0] = *(const float4*)src;
    *(float4*)&xv[4] = *(const float4*)(src + 4);
    ushort8 hi, lo;
#pragma unroll
    for (int i = 0; i < 8; ++i) {
      float hf, lf;
      hi[i] = bf16_rn(xv[i], &hf);
      lo[i] = bf16_rn(xv[i] - hf, &lf);
    }
    unsigned short* dst = &Wc[(size_t)row * 256 + c];
    *(ushort8*)dst = hi;
    *(ushort8*)(dst + 128) = lo;
  } else {
    __shared__ float uS[8][128];
    if (t < 128) {
#pragma unroll
      for (int h = 0; h < 8; ++h) {
        float acc = 0.f;
#pragma unroll
        for (int d = 0; d < 32; ++d)
          acc += W3[(h * 32 + d) * 128 + t] * w[h * 32 + d];
        uS[h][t] = acc * 0.3535533905932738f;  // 1/sqrt(8)
      }
    }
    __syncthreads();
    {
      const int r = t >> 5, c = (t & 31) * 4;
      float4 v = *(float4*)&uS[r][c];
      float vv[4] = {v.x, v.y, v.z, v.w};
      ushort4v hi, lo;
#pragma unroll
      for (int i = 0; i < 4; ++i) {
        float hf, lf;
        hi[i] = bf16_rn(vv[i], &hf);
        lo[i] = bf16_rn(vv[i] - hf, &lf);
      }
      *(ushort4v*)&Wc[(size_t)(512 + r) * 256 + c] = hi;
      *(ushort4v*)&Wc[(size_t)(512 + r) * 256 + 128 + c] = lo;
    }
    const ushort8 z = {};
    for (int i = t; i < 1792; i += 256)  // zero rows 520..575
      *(ushort8*)&Wc[(size_t)520 * 256 + i * 8] = z;
    if (t == 0) atomicExch(bar, 0);
  }
}

__device__ __forceinline__ void grid_barrier(int* bar, int target) {
  __syncthreads();
  if (threadIdx.x == 0) {
    __threadfence();
    atomicAdd(bar, 1);
    int tries = 0;
    while (atomicAdd(bar, 0) < target && ++tries < 10000000)
      __builtin_amdgcn_s_sleep(2);
    __threadfence();
  }
  __syncthreads();
}

__global__ __launch_bounds__(512, 2) void mega_kernel(
    const float* __restrict__ X, const unsigned short* __restrict__ Wc,
    const int* __restrict__ mask, unsigned short* __restrict__ Q2,
    unsigned short* __restrict__ K2, float* __restrict__ Vw,
    float* __restrict__ vws, float* __restrict__ out, int* __restrict__ bar) {
  __shared__ __align__(16) char smem[118272];
  const int bid = blockIdx.x, t = threadIdx.x;
  const int wid = t >> 6, lane = t & 63, g = lane >> 4, r16 = lane & 15;

  // ======== Phase 1: projection ========
  {
    unsigned short (*XS)[264] = (unsigned short(*)[264])smem;          // 67584 B
    unsigned short (*WS)[264] = (unsigned short(*)[264])(smem + 67584);  // 50688 B
    const int row0 = (bid >> 1) * 128, colbase = (bid & 1) * 288;
    {  // stage + bf16-split X rows (one time)
      const int row = t >> 2, cs = (t & 3) * 32;
      const float* xp = &X[(size_t)(row0 + row) * 128 + cs];
      float xv[32];
#pragma unroll
      for (int i = 0; i < 8; ++i) *(float4*)&xv[i * 4] = ((const float4*)xp)[i];
#pragma unroll
      for (int seg = 0; seg < 4; ++seg) {
        ushort8 hi, lo;
#pragma unroll
        for (int e = 0; e < 8; ++e) {
          float hf, lf;
          hi[e] = bf16_rn(xv[seg * 8 + e], &hf);
          lo[e] = bf16_rn(xv[seg * 8 + e] - hf, &lf);
        }
        *(ushort8*)&XS[row][cs + seg * 8] = hi;
        *(ushort8*)&XS[row][128 + cs + seg * 8] = lo;
      }
    }
    __syncthreads();
    const int rowG = wid >> 1, colG = wid & 1;
    for (int cc = 0; cc < 3; ++cc) {
      const int col0 = colbase + cc * 96;
      if (cc) __syncthreads();
#pragma unroll
      for (int i = 0; i < 6; ++i) {  // stage Wc[col0..col0+95][0..255]
        const int flat = i * 512 + t, wr = flat >> 5, cg = (flat & 31) * 8;
        *(ushort8*)&WS[wr][cg] = *(const ushort8*)&Wc[(size_t)(col0 + wr) * 256 + cg];
      }
      __syncthreads();
      f32x4 acc[2][3];
#pragma unroll
      for (int mm = 0; mm < 2; ++mm)
#pragma unroll
        for (int n = 0; n < 3; ++n) acc[mm][n] = (f32x4){0.f, 0.f, 0.f, 0.f};
#pragma unroll
      for (int kc = 0; kc < 256; kc += 64) {
        const int kcx = (kc + 128) & 255;
#pragma unroll
        for (int ks = 0; ks < 2; ++ks) {
          const int ko = kc + ks * 32 + g * 8, kox = kcx + ks * 32 + g * 8;
          bf16x8 a0 = *(const bf16x8*)&XS[rowG * 32 + r16][ko];
          bf16x8 a1 = *(const bf16x8*)&XS[rowG * 32 + 16 + r16][ko];
#pragma unroll
          for (int n = 0; n < 3; ++n) {
            bf16x8 bd = *(const bf16x8*)&WS[colG * 48 + n * 16 + r16][ko];
            bf16x8 bx = *(const bf16x8*)&WS[colG * 48 + n * 16 + r16][kox];
            acc[0][n] = __builtin_amdgcn_mfma_f32_16x16x32_bf16(a0, bd, acc[0][n], 0, 0, 0);
            acc[0][n] = __builtin_amdgcn_mfma_f32_16x16x32_bf16(a0, bx, acc[0][n], 0, 0, 0);
            acc[1][n] = __builtin_amdgcn_mfma_f32_16x16x32_bf16(a1, bd, acc[1][n], 0, 0, 0);
            acc[1][n] = __builtin_amdgcn_mfma_f32_16x16x32_bf16(a1, bx, acc[1][n], 0, 0, 0);
          }
        }
      }
      // epilogue: row = row0 + rowG*32 + mm*16 + g*4 + r; col = col0 + colG*48 + n*16 + r16
#pragma unroll
      for (int n = 0; n < 3; ++n) {
        const int col = col0 + colG * 48 + n * 16 + r16;
#pragma unroll
        for (int mm = 0; mm < 2; ++mm) {
#pragma unroll
          for (int r = 0; r < 4; ++r) {
            const int row = row0 + rowG * 32 + mm * 16 + g * 4 + r;
            const int b = row >> 9, l = row & 511;
            const float val = acc[mm][n][r];
            if (col < 256) {
              const float sv = val * QSCALE;
              float hf, lf;
              const unsigned short hb = bf16_rn(sv, &hf);
              const unsigned short lb = bf16_rn(sv - hf, &lf);
              const size_t o = ((size_t)(b * 8 + (col >> 5)) * 512 + l) * 64 + (col & 31);
              Q2[o] = hb; Q2[o + 32] = lb;
            } else if (col < 512) {
              const int c2 = col - 256;
              float hf, lf;
              const unsigned short hb = bf16_rn(val, &hf);
              const unsigned short lb = bf16_rn(val - hf, &lf);
              const size_t o = ((size_t)(b * 8 + (c2 >> 5)) * 512 + l) * 64 + (c2 & 31);
              K2[o] = hb; K2[o + 32] = lb;
            } else if (col < 520) {
              Vw[(size_t)(b * 8 + (col - 512)) * 512 + l] = val;
            }
          }
        }
      }
    }
  }
  grid_barrier(bar, 256);

  // ======== Phase 2: attention ========
  {
    unsigned short (*KS)[72] = (unsigned short(*)[72])smem;  // 73728 B
    float* VwS = (float*)(smem + 73728);                     // 2048 B
    float* biasS = VwS + 512;                                // 2048 B
    const int b = bid >> 3, h = bid & 7;
    const size_t headoff = (size_t)(b * 8 + h) * 512;
#pragma unroll
    for (int i = 0; i < 8; ++i) {
      const int flat = i * 512 + t, row = flat >> 3, cg = (flat & 7) * 8;
      *(ushort8*)&KS[row][cg] = *(const ushort8*)&K2[(headoff + row) * 64 + cg];
    }
    VwS[t] = Vw[headoff + t];
    biasS[t] = mask[b * 512 + t] ? 0.f : NEG * LOG2E;

    bf16x8 qf[4][2];  // [qtile][hi/lo], wave owns 64 q rows
#pragma unroll
    for (int qt = 0; qt < 4; ++qt)
#pragma unroll
      for (int ks = 0; ks < 2; ++ks)
        qf[qt][ks] = *(const bf16x8*)
            &Q2[(headoff + wid * 64 + qt * 16 + r16) * 64 + ks * 32 + g * 8];
    __syncthreads();

    float m[4], lsum[4], val[4];
#pragma unroll
    for (int qt = 0; qt < 4; ++qt) { m[qt] = -1e30f; lsum[qt] = 0.f; val[qt] = 0.f; }

    for (int c = 0; c < 8; ++c) {
      bf16x8 a0[4], a1[4];
#pragma unroll
      for (int j = 0; j < 4; ++j) {
        a0[j] = *(const bf16x8*)&KS[c * 64 + j * 16 + r16][g * 8];
        a1[j] = *(const bf16x8*)&KS[c * 64 + j * 16 + r16][32 + g * 8];
      }
#pragma unroll
      for (int qt = 0; qt < 4; ++qt) {
        f32x4 sc[4];
#pragma unroll
        for (int j = 0; j < 4; ++j) {
          f32x4 z = (f32x4){0.f, 0.f, 0.f, 0.f};
          z = __builtin_amdgcn_mfma_f32_16x16x32_bf16(a0[j], qf[qt][0], z, 0, 0, 0);
          z = __builtin_amdgcn_mfma_f32_16x16x32_bf16(a0[j], qf[qt][1], z, 0, 0, 0);
          z = __builtin_amdgcn_mfma_f32_16x16x32_bf16(a1[j], qf[qt][0], z, 0, 0, 0);
          sc[j] = z;
        }
        float sb[4][4];
        float cmax = -1e30f;
#pragma unroll
        for (int j = 0; j < 4; ++j) {
          const float4 bsj = *(const float4*)&biasS[c * 64 + j * 16 + g * 4];
          sb[j][0] = sc[j][0] + bsj.x;
          sb[j][1] = sc[j][1] + bsj.y;
          sb[j][2] = sc[j][2] + bsj.z;
          sb[j][3] = sc[j][3] + bsj.w;
#pragma unroll
          for (int r = 0; r < 4; ++r) cmax = fmaxf(cmax, sb[j][r]);
        }
        cmax = fmaxf(cmax, __shfl_xor(cmax, 16));
        cmax = fmaxf(cmax, __shfl_xor(cmax, 32));
        const float mnew = fmaxf(m[qt], cmax);
        const float f = __builtin_amdgcn_exp2f(m[qt] - mnew);
        m[qt] = mnew;
        float ls = lsum[qt] * f, vv = val[qt] * f;
#pragma unroll
        for (int j = 0; j < 4; ++j) {
          const float4 vwj = *(const float4*)&VwS[c * 64 + j * 16 + g * 4];
          const float p0 = __builtin_amdgcn_exp2f(sb[j][0] - mnew);
          const float p1 = __builtin_amdgcn_exp2f(sb[j][1] - mnew);
          const float p2 = __builtin_amdgcn_exp2f(sb[j][2] - mnew);
          const float p3 = __builtin_amdgcn_exp2f(sb[j][3] - mnew);
          ls += (p0 + p1) + (p2 + p3);
          vv = fmaf(p0, vwj.x, vv);
          vv = fmaf(p1, vwj.y, vv);
          vv = fmaf(p2, vwj.z, vv);
          vv = fmaf(p3, vwj.w, vv);
        }
        lsum[qt] = ls; val[qt] = vv;
      }
    }
#pragma unroll
    for (int qt = 0; qt < 4; ++qt) {
      lsum[qt] += __shfl_xor(lsum[qt], 16);
      val[qt]  += __shfl_xor(val[qt], 16);
      lsum[qt] += __shfl_xor(lsum[qt], 32);
      val[qt]  += __shfl_xor(val[qt], 32);
    }
    if (lane < 16) {
#pragma unroll
      for (int qt = 0; qt < 4; ++qt)
        vws[headoff + wid * 64 + qt * 16 + lane] = val[qt] / lsum[qt];
    }
  }
  grid_barrier(bar, 512);

  // ======== Phase 3: final softmax (blocks 0..31) ========
  if (bid < 32) {
    float* redm = (float*)smem;
    float* reds = redm + 8;
    const int b = bid, l = t;
    float v = 0.f;
#pragma unroll
    for (int h = 0; h < 8; ++h) v += vws[(size_t)(b * 8 + h) * 512 + l];
    if (mask[b * 512 + l] == 0) v = NEG;
    float mx = v;
#pragma unroll
    for (int off = 32; off >= 1; off >>= 1) mx = fmaxf(mx, __shfl_xor(mx, off));
    if ((l & 63) == 0) redm[l >> 6] = mx;
    __syncthreads();
    float M = redm[0];
#pragma unroll
    for (int i = 1; i < 8; ++i) M = fmaxf(M, redm[i]);
    const float e = __expf(v - M);
    float sm = e;
#pragma unroll
    for (int off = 32; off >= 1; off >>= 1) sm += __shfl_xor(sm, off);
    if ((l & 63) == 0) reds[l >> 6] = sm;
    __syncthreads();
    float S = 0.f;
#pragma unroll
    for (int i = 0; i < 8; ++i) S += reds[i];
    out[b * 512 + l] = e / S;
  }
}

extern "C" void kernel_launch(void* const* d_in, const int* in_sizes, int n_in,
                              void* d_out, int out_size, void* d_ws, size_t ws_size,
                              hipStream_t stream) {
  const float* X  = (const float*)d_in[0];
  const int*  mk  = (const int*)d_in[1];
  const float* W1 = (const float*)d_in[2];
  const float* W2 = (const float*)d_in[3];
  const float* W3 = (const float*)d_in[4];
  const float* w  = (const float*)d_in[5];
  float* out = (float*)d_out;

  char* ws = (char*)d_ws;
  unsigned short* Wc = (unsigned short*)ws;                 //   576*256*2 = 288 KB
  unsigned short* Q2 = Wc + (size_t)576 * 256;              // 32*8*512*64*2 = 16 MB
  unsigned short* K2 = Q2 + (size_t)32 * 8 * 512 * 64;      // 16 MB
  float* Vw  = (float*)(K2 + (size_t)32 * 8 * 512 * 64);    // 512 KB
  float* vws = Vw + (size_t)32 * 8 * 512;                   // 512 KB
  int* bar   = (int*)(vws + (size_t)32 * 8 * 512);

  convert_w_kernel<<<dim3(33), dim3(256), 0, stream>>>(W1, W2, W3, w, Wc, bar);
  mega_kernel<<<dim3(256), dim3(512), 0, stream>>>(X, Wc, mk, Q2, K2, Vw, vws,
                                                   out, bar);
}